// Round 3
// baseline (202.685 us; speedup 1.0000x reference)
//
#include <hip/hip_runtime.h>

#define NN 131072
#define CIN 256
#define CB 64
#define KNB 27

typedef __attribute__((ext_vector_type(8))) short short8_t;   // 8 x bf16 (4 VGPRs)
typedef __attribute__((ext_vector_type(4))) float f32x4;

__device__ inline unsigned short f2bf(float f) {
    union { float f; unsigned u; } x; x.f = f;
    unsigned r = x.u + 0x7fffu + ((x.u >> 16) & 1u);   // round-to-nearest-even
    return (unsigned short)(r >> 16);
}

__device__ inline f32x4 mfma16(short8_t a, short8_t b, f32x4 c) {
    return __builtin_amdgcn_mfma_f32_16x16x32_bf16(a, b, c, 0, 0, 0);
}

// ---------------------------------------------------------------------------
// prep: fold BN into weights, convert to bf16, pre-swizzle into MFMA frag
// layout: flat index = ((kstep*16-or-4 + tile)*64 + lane)*8 + j
// (A-operand and B-operand per-lane layouts coincide: lane&15 -> m/n index,
//  (lane>>4)*8+j -> k index)
// ---------------------------------------------------------------------------
__global__ __launch_bounds__(256) void prep_kernel(
    const float* __restrict__ w1, const float* __restrict__ w3, const float* __restrict__ w2,
    const float* __restrict__ g1, const float* __restrict__ b1, const float* __restrict__ m1, const float* __restrict__ v1,
    const float* __restrict__ g2, const float* __restrict__ b2, const float* __restrict__ m2, const float* __restrict__ v2,
    const float* __restrict__ g3, const float* __restrict__ b3, const float* __restrict__ m3, const float* __restrict__ v3,
    unsigned short* __restrict__ w1p, unsigned short* __restrict__ w3p, unsigned short* __restrict__ w2p,
    float* __restrict__ bias1, float* __restrict__ bias2, float* __restrict__ bias3)
{
    int t = blockIdx.x * 256 + threadIdx.x;
    if (t < 16384) {                          // w1p: [s:8][t:4][lane:64][j:8], K=256, N=64
        int j = t & 7, lane = (t >> 3) & 63, tt = (t >> 9) & 3, s = t >> 11;
        int c = s * 32 + (lane >> 4) * 8 + j;
        int d = tt * 16 + (lane & 15);
        float sc = g1[d] * rsqrtf(v1[d] + 1e-5f);
        w1p[t] = f2bf(w1[c * CB + d] * sc);
    } else if (t < 16384 + 110592) {          // w3p: [k:27][s:2][t:4][lane:64][j:8]
        int u = t - 16384;
        int j = u & 7, lane = (u >> 3) & 63, tt = (u >> 9) & 3, s = (u >> 11) & 1, k = u >> 12;
        int c = s * 32 + (lane >> 4) * 8 + j;
        int d = tt * 16 + (lane & 15);
        float sc = g2[d] * rsqrtf(v2[d] + 1e-5f);
        w3p[u] = f2bf(w3[(k * CB + c) * CB + d] * sc);
    } else if (t < 143360) {                  // w2p: [s:2][mt:16][lane:64][j:8], K=64, M=256
        int u = t - 126976;
        int j = u & 7, lane = (u >> 3) & 63, mt = (u >> 9) & 15, s = u >> 13;
        int c = s * 32 + (lane >> 4) * 8 + j;
        int d = mt * 16 + (lane & 15);
        float sc = g3[d] * rsqrtf(v3[d] + 1e-5f);
        w2p[u] = f2bf(w2[c * CIN + d] * sc);
    } else if (t < 143744) {                  // biases
        int u = t - 143360;
        if (u < 64)       { float sc = g1[u] * rsqrtf(v1[u] + 1e-5f); bias1[u] = b1[u] - m1[u] * sc; }
        else if (u < 128) { int d = u - 64;  float sc = g2[d] * rsqrtf(v2[d] + 1e-5f); bias2[d] = b2[d] - m2[d] * sc; }
        else              { int d = u - 128; float sc = g3[d] * rsqrtf(v3[d] + 1e-5f); bias3[d] = b3[d] - m3[d] * sc; }
    }
}

// ---------------------------------------------------------------------------
// k1: c1 = relu(data @ w1' + bias1), output bf16 [N,64]
// ---------------------------------------------------------------------------
__global__ __launch_bounds__(256) void k1_conv1x1a(
    const float* __restrict__ data, const unsigned short* __restrict__ w1p,
    const float* __restrict__ bias1, unsigned short* __restrict__ c1b)
{
    __shared__ short8_t w1s[2048];   // 32 KB
    int tid = threadIdx.x;
    const short8_t* wsrc = (const short8_t*)w1p;
#pragma unroll
    for (int i = 0; i < 8; i++) w1s[tid + i * 256] = wsrc[tid + i * 256];

    int lane = tid & 63, wave = tid >> 6;
    int g = lane >> 4, r = lane & 15;
    int rowbase = blockIdx.x * 128 + wave * 32;
    f32x4 acc[2][4] = {};
    __syncthreads();

#pragma unroll
    for (int s = 0; s < 8; s++) {
        short8_t a[2];
#pragma unroll
        for (int sub = 0; sub < 2; sub++) {
            const float* ap = data + (size_t)(rowbase + sub * 16 + r) * CIN + s * 32 + g * 8;
            float4 f0 = *(const float4*)ap;
            float4 f1 = *(const float4*)(ap + 4);
            short8_t av;
            av[0] = (short)f2bf(f0.x); av[1] = (short)f2bf(f0.y);
            av[2] = (short)f2bf(f0.z); av[3] = (short)f2bf(f0.w);
            av[4] = (short)f2bf(f1.x); av[5] = (short)f2bf(f1.y);
            av[6] = (short)f2bf(f1.z); av[7] = (short)f2bf(f1.w);
            a[sub] = av;
        }
#pragma unroll
        for (int t = 0; t < 4; t++) {
            short8_t b = w1s[(s * 4 + t) * 64 + lane];
            acc[0][t] = mfma16(a[0], b, acc[0][t]);
            acc[1][t] = mfma16(a[1], b, acc[1][t]);
        }
    }

#pragma unroll
    for (int sub = 0; sub < 2; sub++)
#pragma unroll
        for (int t = 0; t < 4; t++) {
            int col = t * 16 + r;
            float bs = bias1[col];
#pragma unroll
            for (int i = 0; i < 4; i++) {
                int row = rowbase + sub * 16 + g * 4 + i;
                c1b[row * CB + col] = f2bf(fmaxf(acc[sub][t][i] + bs, 0.f));
            }
        }
}

// ---------------------------------------------------------------------------
// k23: fused conv3x3(+BN+ReLU) and conv1x1b(+BN+residual+ReLU)
// Phase 1: gather conv (a-prefetch depth 1, b loaded just before MFMAs)
// Phase 2: stage c2 bf16 per-wave into LDS (stride 68 -> ~2-way banks)
// Phase 3: transposed GEMM out^T-tiles: A=w2 frags (m=out-col), B=c2 frags
//          (n=row) -> each lane holds 4 contiguous out cols -> float4 RMW
// ---------------------------------------------------------------------------
#define K2_MFMA(aX, bX) \
    _Pragma("unroll") for (int t = 0; t < 4; t++) { \
        acc[0][t] = mfma16(aX[0], bX[t],     acc[0][t]); \
        acc[1][t] = mfma16(aX[2], bX[t],     acc[1][t]); \
        acc[0][t] = mfma16(aX[1], bX[4 + t], acc[0][t]); \
        acc[1][t] = mfma16(aX[3], bX[4 + t], acc[1][t]); \
    }

// compute on aC for step k (b loaded here); prefetch a for k+1 into aN using
// (ixN0,ixN1); refill (ixC0,ixC1) with indices for k+2.
#define K23_STEP(aC, aN, ixC0, ixC1, ixN0, ixN1, k) \
    { \
        short8_t bl[8]; \
        const short8_t* bp = bbase + (size_t)(k) * 512; \
        _Pragma("unroll") for (int f = 0; f < 8; f++) bl[f] = bp[f * 64 + lane]; \
        if ((k) < 26) { \
            const short8_t* p0 = (const short8_t*)(c1b + (size_t)(ixN0) * CB); \
            const short8_t* p1 = (const short8_t*)(c1b + (size_t)(ixN1) * CB); \
            aN[0] = p0[g]; aN[1] = p0[4 + g]; aN[2] = p1[g]; aN[3] = p1[4 + g]; \
        } \
        if ((k) < 25) { ixC0 = nidx[lr0 * KNB + (k) + 2]; ixC1 = nidx[lr1 * KNB + (k) + 2]; } \
        K2_MFMA(aC, bl) \
    }

__global__ __launch_bounds__(256) void k23_fused(
    const unsigned short* __restrict__ c1b, const int* __restrict__ neigh,
    const unsigned short* __restrict__ w3p, const float* __restrict__ bias2,
    const unsigned short* __restrict__ w2p, const float* __restrict__ bias3,
    const float* __restrict__ data, float* __restrict__ out)
{
    __shared__ __align__(16) char shraw[17408];   // nidx (13824) then cstage (17408)
    int* nidx = (int*)shraw;
    int tid = threadIdx.x;
    int rowbase = blockIdx.x * 128;

    // coalesced cooperative load of this block's neighbor table
    const int4* nsrc = (const int4*)(neigh + (size_t)rowbase * KNB);
#pragma unroll
    for (int i = 0; i < 4; i++) {
        int p = tid + i * 256;
        if (p < 864) ((int4*)nidx)[p] = nsrc[p];
    }

    int lane = tid & 63, wave = tid >> 6;
    int g = lane >> 4, r = lane & 15;
    int lr0 = wave * 32 + r, lr1 = lr0 + 16;
    __syncthreads();

    const short8_t* bbase = (const short8_t*)w3p;
    f32x4 acc[2][4] = {};
    short8_t aA[4], aB[4];
    int ixA0, ixA1, ixB0, ixB1;

    // prologue: idx k=0,1; gather a(k=0)
    ixA0 = nidx[lr0 * KNB + 0]; ixA1 = nidx[lr1 * KNB + 0];
    ixB0 = nidx[lr0 * KNB + 1]; ixB1 = nidx[lr1 * KNB + 1];
    {
        const short8_t* p0 = (const short8_t*)(c1b + (size_t)ixA0 * CB);
        const short8_t* p1 = (const short8_t*)(c1b + (size_t)ixA1 * CB);
        aA[0] = p0[g]; aA[1] = p0[4 + g]; aA[2] = p1[g]; aA[3] = p1[4 + g];
    }

    for (int kk = 0; kk < 13; kk++) {
        int k0 = kk * 2;
        K23_STEP(aA, aB, ixA0, ixA1, ixB0, ixB1, k0)
        K23_STEP(aB, aA, ixB0, ixB1, ixA0, ixA1, k0 + 1)
    }
    K23_STEP(aA, aB, ixA0, ixA1, ixB0, ixB1, 26)

    // ---- phase 2: relu(bn(c2)) -> bf16 -> per-wave LDS (stride 68) ----
    __syncthreads();   // all waves done reading nidx before overwrite
    unsigned short* cst = (unsigned short*)shraw + wave * 2176;   // 4352 B/wave
#pragma unroll
    for (int sub = 0; sub < 2; sub++)
#pragma unroll
        for (int t = 0; t < 4; t++) {
            int col = t * 16 + r;
            float bs = bias2[col];
#pragma unroll
            for (int i = 0; i < 4; i++) {
                int row = sub * 16 + g * 4 + i;
                cst[row * 68 + col] = f2bf(fmaxf(acc[sub][t][i] + bs, 0.f));
            }
        }
    __syncthreads();

    // ---- phase 3: out-tiles transposed; B-frags (c2) from LDS ----
    short8_t bfr[2][2];
#pragma unroll
    for (int sub = 0; sub < 2; sub++)
#pragma unroll
        for (int s = 0; s < 2; s++)
            bfr[sub][s] = *(const short8_t*)(cst + (sub * 16 + r) * 68 + s * 32 + g * 8);

    const short8_t* abase = (const short8_t*)w2p;
#pragma unroll
    for (int h = 0; h < 2; h++) {
        f32x4 acc2[2][8] = {};
#pragma unroll
        for (int mt = 0; mt < 8; mt++) {
            short8_t a0 = abase[(h * 8 + mt) * 64 + lane];          // s=0
            short8_t a1 = abase[(16 + h * 8 + mt) * 64 + lane];     // s=1
            acc2[0][mt] = mfma16(a0, bfr[0][0], acc2[0][mt]);
            acc2[0][mt] = mfma16(a1, bfr[0][1], acc2[0][mt]);
            acc2[1][mt] = mfma16(a0, bfr[1][0], acc2[1][mt]);
            acc2[1][mt] = mfma16(a1, bfr[1][1], acc2[1][mt]);
        }
        // epilogue: lane (g,r) holds out[row=...+r][cols mt*16+g*4 .. +3]
#pragma unroll
        for (int sub = 0; sub < 2; sub++)
#pragma unroll
            for (int mt = 0; mt < 8; mt++) {
                int col0 = (h * 8 + mt) * 16 + g * 4;
                int rowg = rowbase + wave * 32 + sub * 16 + r;
                float4 bs = *(const float4*)(bias3 + col0);
                float4 dv = *(const float4*)(data + (size_t)rowg * CIN + col0);
                f32x4 v = acc2[sub][mt];
                float4 res;
                res.x = fmaxf(v[0] + bs.x + dv.x, 0.f);
                res.y = fmaxf(v[1] + bs.y + dv.y, 0.f);
                res.z = fmaxf(v[2] + bs.z + dv.z, 0.f);
                res.w = fmaxf(v[3] + bs.w + dv.w, 0.f);
                *(float4*)(out + (size_t)rowg * CIN + col0) = res;
            }
    }
}

extern "C" void kernel_launch(void* const* d_in, const int* in_sizes, int n_in,
                              void* d_out, int out_size, void* d_ws, size_t ws_size,
                              hipStream_t stream)
{
    const float* data = (const float*)d_in[0];
    const int* neigh  = (const int*)d_in[1];
    const float* w1 = (const float*)d_in[3];
    const float* g1 = (const float*)d_in[4];
    const float* b1 = (const float*)d_in[5];
    const float* m1 = (const float*)d_in[6];
    const float* v1 = (const float*)d_in[7];
    const float* w3 = (const float*)d_in[8];
    const float* g2 = (const float*)d_in[9];
    const float* b2 = (const float*)d_in[10];
    const float* m2 = (const float*)d_in[11];
    const float* v2 = (const float*)d_in[12];
    const float* w2 = (const float*)d_in[13];
    const float* g3 = (const float*)d_in[14];
    const float* b3 = (const float*)d_in[15];
    const float* m3 = (const float*)d_in[16];
    const float* v3 = (const float*)d_in[17];
    float* out = (float*)d_out;

    char* ws = (char*)d_ws;
    unsigned short* c1b = (unsigned short*)ws;                              // 16 MB
    unsigned short* w1p = (unsigned short*)(ws + 33554432);                 // 32 KB
    unsigned short* w3p = (unsigned short*)(ws + 33554432 + 32768);         // 216 KB
    unsigned short* w2p = (unsigned short*)(ws + 33554432 + 32768 + 221184);// 32 KB
    float* bias1 = (float*)(ws + 33554432 + 32768 + 221184 + 32768);
    float* bias2 = bias1 + 64;
    float* bias3 = bias1 + 128;

    int n = in_sizes[0] / CIN;   // 131072

    hipLaunchKernelGGL(prep_kernel, dim3(562), dim3(256), 0, stream,
                       w1, w3, w2, g1, b1, m1, v1, g2, b2, m2, v2, g3, b3, m3, v3,
                       w1p, w3p, w2p, bias1, bias2, bias3);
    hipLaunchKernelGGL(k1_conv1x1a, dim3(n / 128), dim3(256), 0, stream, data, w1p, bias1, c1b);
    hipLaunchKernelGGL(k23_fused,   dim3(n / 128), dim3(256), 0, stream,
                       c1b, neigh, w3p, bias2, w2p, bias3, data, out);
}

// Round 4
// 189.977 us; speedup vs baseline: 1.0669x; 1.0669x over previous
//
#include <hip/hip_runtime.h>

#define NN 131072
#define CIN 256
#define CB 64
#define KNB 27

typedef __attribute__((ext_vector_type(8))) short short8_t;   // 8 x bf16 (4 VGPRs)
typedef __attribute__((ext_vector_type(4))) float f32x4;

__device__ inline unsigned short f2bf(float f) {
    union { float f; unsigned u; } x; x.f = f;
    unsigned r = x.u + 0x7fffu + ((x.u >> 16) & 1u);   // round-to-nearest-even
    return (unsigned short)(r >> 16);
}

__device__ inline f32x4 mfma16(short8_t a, short8_t b, f32x4 c) {
    return __builtin_amdgcn_mfma_f32_16x16x32_bf16(a, b, c, 0, 0, 0);
}

// ---------------------------------------------------------------------------
// prep: fold BN into weights, convert to bf16, pre-swizzle into MFMA frag
// layout: flat index = ((kstep*T + tile)*64 + lane)*8 + j
// (A- and B-operand per-lane layouts coincide: lane&15 -> m/n, (lane>>4)*8+j -> k)
// ---------------------------------------------------------------------------
__global__ __launch_bounds__(256) void prep_kernel(
    const float* __restrict__ w1, const float* __restrict__ w3, const float* __restrict__ w2,
    const float* __restrict__ g1, const float* __restrict__ b1, const float* __restrict__ m1, const float* __restrict__ v1,
    const float* __restrict__ g2, const float* __restrict__ b2, const float* __restrict__ m2, const float* __restrict__ v2,
    const float* __restrict__ g3, const float* __restrict__ b3, const float* __restrict__ m3, const float* __restrict__ v3,
    unsigned short* __restrict__ w1p, unsigned short* __restrict__ w3p, unsigned short* __restrict__ w2p,
    float* __restrict__ bias1, float* __restrict__ bias2, float* __restrict__ bias3)
{
    int t = blockIdx.x * 256 + threadIdx.x;
    if (t < 16384) {                          // w1p: [s:8][t:4][lane:64][j:8], K=256, N=64
        int j = t & 7, lane = (t >> 3) & 63, tt = (t >> 9) & 3, s = t >> 11;
        int c = s * 32 + (lane >> 4) * 8 + j;
        int d = tt * 16 + (lane & 15);
        float sc = g1[d] * rsqrtf(v1[d] + 1e-5f);
        w1p[t] = f2bf(w1[c * CB + d] * sc);
    } else if (t < 16384 + 110592) {          // w3p: [k:27][s:2][t:4][lane:64][j:8]
        int u = t - 16384;
        int j = u & 7, lane = (u >> 3) & 63, tt = (u >> 9) & 3, s = (u >> 11) & 1, k = u >> 12;
        int c = s * 32 + (lane >> 4) * 8 + j;
        int d = tt * 16 + (lane & 15);
        float sc = g2[d] * rsqrtf(v2[d] + 1e-5f);
        w3p[u] = f2bf(w3[(k * CB + c) * CB + d] * sc);
    } else if (t < 143360) {                  // w2p: [s:2][mt:16][lane:64][j:8], K=64, M=256
        int u = t - 126976;
        int j = u & 7, lane = (u >> 3) & 63, mt = (u >> 9) & 15, s = u >> 13;
        int c = s * 32 + (lane >> 4) * 8 + j;
        int d = mt * 16 + (lane & 15);
        float sc = g3[d] * rsqrtf(v3[d] + 1e-5f);
        w2p[u] = f2bf(w2[c * CIN + d] * sc);
    } else if (t < 143744) {                  // biases
        int u = t - 143360;
        if (u < 64)       { float sc = g1[u] * rsqrtf(v1[u] + 1e-5f); bias1[u] = b1[u] - m1[u] * sc; }
        else if (u < 128) { int d = u - 64;  float sc = g2[d] * rsqrtf(v2[d] + 1e-5f); bias2[d] = b2[d] - m2[d] * sc; }
        else              { int d = u - 128; float sc = g3[d] * rsqrtf(v3[d] + 1e-5f); bias3[d] = b3[d] - m3[d] * sc; }
    }
}

// ---------------------------------------------------------------------------
// k1: c1 = relu(data @ w1' + bias1), output bf16 [N,64]
// ---------------------------------------------------------------------------
__global__ __launch_bounds__(256) void k1_conv1x1a(
    const float* __restrict__ data, const unsigned short* __restrict__ w1p,
    const float* __restrict__ bias1, unsigned short* __restrict__ c1b)
{
    __shared__ short8_t w1s[2048];   // 32 KB
    int tid = threadIdx.x;
    const short8_t* wsrc = (const short8_t*)w1p;
#pragma unroll
    for (int i = 0; i < 8; i++) w1s[tid + i * 256] = wsrc[tid + i * 256];

    int lane = tid & 63, wave = tid >> 6;
    int g = lane >> 4, r = lane & 15;
    int rowbase = blockIdx.x * 128 + wave * 32;
    f32x4 acc[2][4] = {};
    __syncthreads();

#pragma unroll
    for (int s = 0; s < 8; s++) {
        short8_t a[2];
#pragma unroll
        for (int sub = 0; sub < 2; sub++) {
            const float* ap = data + (size_t)(rowbase + sub * 16 + r) * CIN + s * 32 + g * 8;
            float4 f0 = *(const float4*)ap;
            float4 f1 = *(const float4*)(ap + 4);
            short8_t av;
            av[0] = (short)f2bf(f0.x); av[1] = (short)f2bf(f0.y);
            av[2] = (short)f2bf(f0.z); av[3] = (short)f2bf(f0.w);
            av[4] = (short)f2bf(f1.x); av[5] = (short)f2bf(f1.y);
            av[6] = (short)f2bf(f1.z); av[7] = (short)f2bf(f1.w);
            a[sub] = av;
        }
#pragma unroll
        for (int t = 0; t < 4; t++) {
            short8_t b = w1s[(s * 4 + t) * 64 + lane];
            acc[0][t] = mfma16(a[0], b, acc[0][t]);
            acc[1][t] = mfma16(a[1], b, acc[1][t]);
        }
    }

#pragma unroll
    for (int sub = 0; sub < 2; sub++)
#pragma unroll
        for (int t = 0; t < 4; t++) {
            int col = t * 16 + r;
            float bs = bias1[col];
#pragma unroll
            for (int i = 0; i < 4; i++) {
                int row = rowbase + sub * 16 + g * 4 + i;
                c1b[row * CB + col] = f2bf(fmaxf(acc[sub][t][i] + bs, 0.f));
            }
        }
}

// ---------------------------------------------------------------------------
// k2 v3: c2 = relu(sum_k c1[neigh[n,k]] @ w3'[k] + bias2), bf16 [N,64]
// Barrier-free; explicit pipeline: b(k+1) loaded BEFORE gathers(k+2) each
// step so the counted vmcnt for b(k) leaves 2 gather sets in flight.
// A-sets rotate period 3 (depth-2 gather prefetch), B-sets period 2.
// ---------------------------------------------------------------------------
#define KCLAMP(x) ((x) < 26 ? (x) : 26)

#define K2_LOADB(bN, kc) { \
    const short8_t* bp_ = bbase + (size_t)(kc) * 512; \
    bN[0] = bp_[lane];       bN[1] = bp_[64 + lane]; \
    bN[2] = bp_[128 + lane]; bN[3] = bp_[192 + lane]; \
    bN[4] = bp_[256 + lane]; bN[5] = bp_[320 + lane]; \
    bN[6] = bp_[384 + lane]; bN[7] = bp_[448 + lane]; }

#define K2_GATH(aN, kc) { \
    int i0_ = nidx[lr0 * KNB + (kc)]; \
    int i1_ = nidx[lr1 * KNB + (kc)]; \
    const short8_t* p0_ = (const short8_t*)(c1b + (size_t)i0_ * CB); \
    const short8_t* p1_ = (const short8_t*)(c1b + (size_t)i1_ * CB); \
    aN[0] = p0_[g]; aN[1] = p0_[4 + g]; aN[2] = p1_[g]; aN[3] = p1_[4 + g]; }

#define K2_MF(aC, bC) { \
    _Pragma("unroll") for (int t = 0; t < 4; t++) { \
        acc[0][t] = mfma16(aC[0], bC[t],     acc[0][t]); \
        acc[1][t] = mfma16(aC[2], bC[t],     acc[1][t]); \
        acc[0][t] = mfma16(aC[1], bC[4 + t], acc[0][t]); \
        acc[1][t] = mfma16(aC[3], bC[4 + t], acc[1][t]); } }

#define K2_STEP(aC, bC, aN, bN, k) \
    K2_LOADB(bN, KCLAMP((k) + 1)) \
    K2_GATH(aN, KCLAMP((k) + 2)) \
    K2_MF(aC, bC)

__global__ __launch_bounds__(256) void k2_conv3x3(
    const unsigned short* __restrict__ c1b, const int* __restrict__ neigh,
    const unsigned short* __restrict__ w3p, const float* __restrict__ bias2,
    unsigned short* __restrict__ c2b)
{
    __shared__ int nidx[128 * KNB];          // 13824 B
    int tid = threadIdx.x;
    int rowbase = blockIdx.x * 128;

    const int4* nsrc = (const int4*)(neigh + (size_t)rowbase * KNB);
#pragma unroll
    for (int i = 0; i < 4; i++) {
        int p = tid + i * 256;
        if (p < 864) ((int4*)nidx)[p] = nsrc[p];
    }

    int lane = tid & 63, wave = tid >> 6;
    int g = lane >> 4, r = lane & 15;
    int lr0 = wave * 32 + r, lr1 = lr0 + 16;
    __syncthreads();

    const short8_t* bbase = (const short8_t*)w3p;
    f32x4 acc[2][4] = {};
    short8_t aA[4], aB[4], aC[4], bX[8], bY[8];

    // prologue FIFO: bX(0), gathers k=0 (aA), k=1 (aB)
    K2_LOADB(bX, 0)
    K2_GATH(aA, 0)
    K2_GATH(aB, 1)

    for (int kb = 0; kb < 24; kb += 6) {
        K2_STEP(aA, bX, aC, bY, kb + 0)
        K2_STEP(aB, bY, aA, bX, kb + 1)
        K2_STEP(aC, bX, aB, bY, kb + 2)
        K2_STEP(aA, bY, aC, bX, kb + 3)
        K2_STEP(aB, bX, aA, bY, kb + 4)
        K2_STEP(aC, bY, aB, bX, kb + 5)
    }
    K2_STEP(aA, bX, aC, bY, 24)
    K2_STEP(aB, bY, aA, bX, 25)
    K2_STEP(aC, bX, aB, bY, 26)

#pragma unroll
    for (int sub = 0; sub < 2; sub++)
#pragma unroll
        for (int t = 0; t < 4; t++) {
            int col = t * 16 + r;
            float bs = bias2[col];
#pragma unroll
            for (int i = 0; i < 4; i++) {
                int row = rowbase + wave * 32 + sub * 16 + g * 4 + i;
                c2b[row * CB + col] = f2bf(fmaxf(acc[sub][t][i] + bs, 0.f));
            }
        }
}

// ---------------------------------------------------------------------------
// k3 v2: out = relu(c2 @ w2' + bias3 + data), fp32 [N,256]
// Transposed GEMM (A = w2 frags, m = out-col; B = c2 row frags, n = row)
// -> lane holds 4 contiguous out cols -> direct float4 residual RMW.
// LDS-free, barrier-free. 32 rows/block, wave w owns cols [w*64, w*64+64).
// ---------------------------------------------------------------------------
__global__ __launch_bounds__(256) void k3_conv1x1b(
    const unsigned short* __restrict__ c2b, const unsigned short* __restrict__ w2p,
    const float* __restrict__ bias3, const float* __restrict__ data,
    float* __restrict__ out)
{
    int tid = threadIdx.x;
    int lane = tid & 63, wave = tid >> 6;
    int g = lane >> 4, r = lane & 15;
    int rowbase = blockIdx.x * 32;

    const short8_t* abase = (const short8_t*)w2p;
    short8_t bfr[2][2];
#pragma unroll
    for (int sub = 0; sub < 2; sub++)
#pragma unroll
        for (int s = 0; s < 2; s++)
            bfr[sub][s] = *(const short8_t*)(c2b + (size_t)(rowbase + sub * 16 + r) * CB + s * 32 + g * 8);

    f32x4 acc2[2][4] = {};
#pragma unroll
    for (int mt = 0; mt < 4; mt++) {
        short8_t a0 = abase[(wave * 4 + mt) * 64 + lane];          // s=0
        short8_t a1 = abase[(16 + wave * 4 + mt) * 64 + lane];     // s=1
        acc2[0][mt] = mfma16(a0, bfr[0][0], acc2[0][mt]);
        acc2[0][mt] = mfma16(a1, bfr[0][1], acc2[0][mt]);
        acc2[1][mt] = mfma16(a0, bfr[1][0], acc2[1][mt]);
        acc2[1][mt] = mfma16(a1, bfr[1][1], acc2[1][mt]);
    }

#pragma unroll
    for (int sub = 0; sub < 2; sub++)
#pragma unroll
        for (int mt = 0; mt < 4; mt++) {
            int col0 = (wave * 4 + mt) * 16 + g * 4;
            int rowg = rowbase + sub * 16 + r;
            float4 bs = *(const float4*)(bias3 + col0);
            float4 dv = *(const float4*)(data + (size_t)rowg * CIN + col0);
            f32x4 v = acc2[sub][mt];
            float4 res;
            res.x = fmaxf(v[0] + bs.x + dv.x, 0.f);
            res.y = fmaxf(v[1] + bs.y + dv.y, 0.f);
            res.z = fmaxf(v[2] + bs.z + dv.z, 0.f);
            res.w = fmaxf(v[3] + bs.w + dv.w, 0.f);
            *(float4*)(out + (size_t)rowg * CIN + col0) = res;
        }
}

extern "C" void kernel_launch(void* const* d_in, const int* in_sizes, int n_in,
                              void* d_out, int out_size, void* d_ws, size_t ws_size,
                              hipStream_t stream)
{
    const float* data = (const float*)d_in[0];
    const int* neigh  = (const int*)d_in[1];
    const float* w1 = (const float*)d_in[3];
    const float* g1 = (const float*)d_in[4];
    const float* b1 = (const float*)d_in[5];
    const float* m1 = (const float*)d_in[6];
    const float* v1 = (const float*)d_in[7];
    const float* w3 = (const float*)d_in[8];
    const float* g2 = (const float*)d_in[9];
    const float* b2 = (const float*)d_in[10];
    const float* m2 = (const float*)d_in[11];
    const float* v2 = (const float*)d_in[12];
    const float* w2 = (const float*)d_in[13];
    const float* g3 = (const float*)d_in[14];
    const float* b3 = (const float*)d_in[15];
    const float* m3 = (const float*)d_in[16];
    const float* v3 = (const float*)d_in[17];
    float* out = (float*)d_out;

    char* ws = (char*)d_ws;
    unsigned short* c1b = (unsigned short*)ws;                              // 16 MB
    unsigned short* c2b = (unsigned short*)(ws + 16777216);                 // 16 MB
    unsigned short* w1p = (unsigned short*)(ws + 33554432);                 // 32 KB
    unsigned short* w3p = (unsigned short*)(ws + 33554432 + 32768);         // 216 KB
    unsigned short* w2p = (unsigned short*)(ws + 33554432 + 32768 + 221184);// 32 KB
    float* bias1 = (float*)(ws + 33554432 + 32768 + 221184 + 32768);
    float* bias2 = bias1 + 64;
    float* bias3 = bias1 + 128;

    int n = in_sizes[0] / CIN;   // 131072

    hipLaunchKernelGGL(prep_kernel, dim3(562), dim3(256), 0, stream,
                       w1, w3, w2, g1, b1, m1, v1, g2, b2, m2, v2, g3, b3, m3, v3,
                       w1p, w3p, w2p, bias1, bias2, bias3);
    hipLaunchKernelGGL(k1_conv1x1a, dim3(n / 128), dim3(256), 0, stream, data, w1p, bias1, c1b);
    hipLaunchKernelGGL(k2_conv3x3,  dim3(n / 128), dim3(256), 0, stream, c1b, neigh, w3p, bias2, c2b);
    hipLaunchKernelGGL(k3_conv1x1b, dim3(n / 32),  dim3(256), 0, stream, c2b, w2p, bias3, data, out);
}

// Round 5
// 187.660 us; speedup vs baseline: 1.0801x; 1.0123x over previous
//
#include <hip/hip_runtime.h>

#define NN 131072
#define CIN 256
#define CB 64
#define KNB 27

typedef __attribute__((ext_vector_type(8))) short short8_t;   // 8 x bf16 (4 VGPRs)
typedef __attribute__((ext_vector_type(4))) float f32x4;

__device__ inline unsigned short f2bf(float f) {
    union { float f; unsigned u; } x; x.f = f;
    unsigned r = x.u + 0x7fffu + ((x.u >> 16) & 1u);   // round-to-nearest-even
    return (unsigned short)(r >> 16);
}

__device__ inline f32x4 mfma16(short8_t a, short8_t b, f32x4 c) {
    return __builtin_amdgcn_mfma_f32_16x16x32_bf16(a, b, c, 0, 0, 0);
}

// ---------------------------------------------------------------------------
// prep: fold BN into weights, convert to bf16, pre-swizzle into MFMA frag
// layout: flat index = ((kstep*T + tile)*64 + lane)*8 + j
// (A- and B-operand per-lane layouts coincide: lane&15 -> m/n, (lane>>4)*8+j -> k)
// ---------------------------------------------------------------------------
__global__ __launch_bounds__(256) void prep_kernel(
    const float* __restrict__ w1, const float* __restrict__ w3, const float* __restrict__ w2,
    const float* __restrict__ g1, const float* __restrict__ b1, const float* __restrict__ m1, const float* __restrict__ v1,
    const float* __restrict__ g2, const float* __restrict__ b2, const float* __restrict__ m2, const float* __restrict__ v2,
    const float* __restrict__ g3, const float* __restrict__ b3, const float* __restrict__ m3, const float* __restrict__ v3,
    unsigned short* __restrict__ w1p, unsigned short* __restrict__ w3p, unsigned short* __restrict__ w2p,
    float* __restrict__ bias1, float* __restrict__ bias2, float* __restrict__ bias3)
{
    int t = blockIdx.x * 256 + threadIdx.x;
    if (t < 16384) {                          // w1p: [s:8][t:4][lane:64][j:8], K=256, N=64
        int j = t & 7, lane = (t >> 3) & 63, tt = (t >> 9) & 3, s = t >> 11;
        int c = s * 32 + (lane >> 4) * 8 + j;
        int d = tt * 16 + (lane & 15);
        float sc = g1[d] * rsqrtf(v1[d] + 1e-5f);
        w1p[t] = f2bf(w1[c * CB + d] * sc);
    } else if (t < 16384 + 110592) {          // w3p: [k:27][s:2][t:4][lane:64][j:8]
        int u = t - 16384;
        int j = u & 7, lane = (u >> 3) & 63, tt = (u >> 9) & 3, s = (u >> 11) & 1, k = u >> 12;
        int c = s * 32 + (lane >> 4) * 8 + j;
        int d = tt * 16 + (lane & 15);
        float sc = g2[d] * rsqrtf(v2[d] + 1e-5f);
        w3p[u] = f2bf(w3[(k * CB + c) * CB + d] * sc);
    } else if (t < 143360) {                  // w2p: [s:2][mt:16][lane:64][j:8], K=64, M=256
        int u = t - 126976;
        int j = u & 7, lane = (u >> 3) & 63, mt = (u >> 9) & 15, s = u >> 13;
        int c = s * 32 + (lane >> 4) * 8 + j;
        int d = mt * 16 + (lane & 15);
        float sc = g3[d] * rsqrtf(v3[d] + 1e-5f);
        w2p[u] = f2bf(w2[c * CIN + d] * sc);
    } else if (t < 143744) {                  // biases
        int u = t - 143360;
        if (u < 64)       { float sc = g1[u] * rsqrtf(v1[u] + 1e-5f); bias1[u] = b1[u] - m1[u] * sc; }
        else if (u < 128) { int d = u - 64;  float sc = g2[d] * rsqrtf(v2[d] + 1e-5f); bias2[d] = b2[d] - m2[d] * sc; }
        else              { int d = u - 128; float sc = g3[d] * rsqrtf(v3[d] + 1e-5f); bias3[d] = b3[d] - m3[d] * sc; }
    }
}

// ---------------------------------------------------------------------------
// k1: c1 = relu(data @ w1' + bias1), output bf16 [N,64]
// ---------------------------------------------------------------------------
__global__ __launch_bounds__(256) void k1_conv1x1a(
    const float* __restrict__ data, const unsigned short* __restrict__ w1p,
    const float* __restrict__ bias1, unsigned short* __restrict__ c1b)
{
    __shared__ short8_t w1s[2048];   // 32 KB
    int tid = threadIdx.x;
    const short8_t* wsrc = (const short8_t*)w1p;
#pragma unroll
    for (int i = 0; i < 8; i++) w1s[tid + i * 256] = wsrc[tid + i * 256];

    int lane = tid & 63, wave = tid >> 6;
    int g = lane >> 4, r = lane & 15;
    int rowbase = blockIdx.x * 128 + wave * 32;
    f32x4 acc[2][4] = {};
    __syncthreads();

#pragma unroll
    for (int s = 0; s < 8; s++) {
        short8_t a[2];
#pragma unroll
        for (int sub = 0; sub < 2; sub++) {
            const float* ap = data + (size_t)(rowbase + sub * 16 + r) * CIN + s * 32 + g * 8;
            float4 f0 = *(const float4*)ap;
            float4 f1 = *(const float4*)(ap + 4);
            short8_t av;
            av[0] = (short)f2bf(f0.x); av[1] = (short)f2bf(f0.y);
            av[2] = (short)f2bf(f0.z); av[3] = (short)f2bf(f0.w);
            av[4] = (short)f2bf(f1.x); av[5] = (short)f2bf(f1.y);
            av[6] = (short)f2bf(f1.z); av[7] = (short)f2bf(f1.w);
            a[sub] = av;
        }
#pragma unroll
        for (int t = 0; t < 4; t++) {
            short8_t b = w1s[(s * 4 + t) * 64 + lane];
            acc[0][t] = mfma16(a[0], b, acc[0][t]);
            acc[1][t] = mfma16(a[1], b, acc[1][t]);
        }
    }

#pragma unroll
    for (int sub = 0; sub < 2; sub++)
#pragma unroll
        for (int t = 0; t < 4; t++) {
            int col = t * 16 + r;
            float bs = bias1[col];
#pragma unroll
            for (int i = 0; i < 4; i++) {
                int row = rowbase + sub * 16 + g * 4 + i;
                c1b[row * CB + col] = f2bf(fmaxf(acc[sub][t][i] + bs, 0.f));
            }
        }
}

// ---------------------------------------------------------------------------
// k2 v5: c2 = relu(sum_k c1[neigh[n,k]] @ w3'[k] + bias2), bf16 [N,64]
// SINGLE-WAVE blocks (64 threads, 32 rows) -> 4096 blocks -> 2-3x resident
// waves/CU vs 4-wave blocks. Same per-wave structure as v3 (b from L2,
// depth-2 gather rotation); concurrency comes from block count.
// ---------------------------------------------------------------------------
#define KCLAMP(x) ((x) < 26 ? (x) : 26)

#define K2_LOADB(bN, kc) { \
    const short8_t* bp_ = bbase + (size_t)(kc) * 512; \
    bN[0] = bp_[lane];       bN[1] = bp_[64 + lane]; \
    bN[2] = bp_[128 + lane]; bN[3] = bp_[192 + lane]; \
    bN[4] = bp_[256 + lane]; bN[5] = bp_[320 + lane]; \
    bN[6] = bp_[384 + lane]; bN[7] = bp_[448 + lane]; }

#define K2_GATH(aN, kc) { \
    int i0_ = nidx[lr0 * KNB + (kc)]; \
    int i1_ = nidx[lr1 * KNB + (kc)]; \
    const short8_t* p0_ = (const short8_t*)(c1b + (size_t)i0_ * CB); \
    const short8_t* p1_ = (const short8_t*)(c1b + (size_t)i1_ * CB); \
    aN[0] = p0_[g]; aN[1] = p0_[4 + g]; aN[2] = p1_[g]; aN[3] = p1_[4 + g]; }

#define K2_MF(aC, bC) { \
    _Pragma("unroll") for (int t = 0; t < 4; t++) { \
        acc[0][t] = mfma16(aC[0], bC[t],     acc[0][t]); \
        acc[1][t] = mfma16(aC[2], bC[t],     acc[1][t]); \
        acc[0][t] = mfma16(aC[1], bC[4 + t], acc[0][t]); \
        acc[1][t] = mfma16(aC[3], bC[4 + t], acc[1][t]); } }

#define K2_STEP(aC, bC, aN, bN, k) \
    K2_LOADB(bN, KCLAMP((k) + 1)) \
    K2_GATH(aN, KCLAMP((k) + 2)) \
    K2_MF(aC, bC)

__global__ __launch_bounds__(64, 4) void k2_conv3x3(
    const unsigned short* __restrict__ c1b, const int* __restrict__ neigh,
    const unsigned short* __restrict__ w3p, const float* __restrict__ bias2,
    unsigned short* __restrict__ c2b)
{
    __shared__ int nidx[32 * KNB];           // 3456 B
    int tid = threadIdx.x;
    int rowbase = blockIdx.x * 32;

    // coalesced cooperative load of this block's neighbor table (864 ints)
    const int4* nsrc = (const int4*)(neigh + (size_t)rowbase * KNB);
#pragma unroll
    for (int i = 0; i < 4; i++) {
        int p = tid + i * 64;
        if (p < 216) ((int4*)nidx)[p] = nsrc[p];
    }

    int lane = tid & 63;
    int g = lane >> 4, r = lane & 15;
    int lr0 = r, lr1 = 16 + r;
    __syncthreads();

    const short8_t* bbase = (const short8_t*)w3p;
    f32x4 acc[2][4] = {};
    short8_t aA[4], aB[4], aC[4], bX[8], bY[8];

    // prologue FIFO: bX(0), gathers k=0 (aA), k=1 (aB)
    K2_LOADB(bX, 0)
    K2_GATH(aA, 0)
    K2_GATH(aB, 1)

    for (int kb = 0; kb < 24; kb += 6) {
        K2_STEP(aA, bX, aC, bY, kb + 0)
        K2_STEP(aB, bY, aA, bX, kb + 1)
        K2_STEP(aC, bX, aB, bY, kb + 2)
        K2_STEP(aA, bY, aC, bX, kb + 3)
        K2_STEP(aB, bX, aA, bY, kb + 4)
        K2_STEP(aC, bY, aB, bX, kb + 5)
    }
    K2_STEP(aA, bX, aC, bY, 24)
    K2_STEP(aB, bY, aA, bX, 25)
    K2_STEP(aC, bX, aB, bY, 26)

#pragma unroll
    for (int sub = 0; sub < 2; sub++)
#pragma unroll
        for (int t = 0; t < 4; t++) {
            int col = t * 16 + r;
            float bs = bias2[col];
#pragma unroll
            for (int i = 0; i < 4; i++) {
                int row = rowbase + sub * 16 + g * 4 + i;
                c2b[row * CB + col] = f2bf(fmaxf(acc[sub][t][i] + bs, 0.f));
            }
        }
}

// ---------------------------------------------------------------------------
// k3 v2: out = relu(c2 @ w2' + bias3 + data), fp32 [N,256]
// Transposed GEMM (A = w2 frags, m = out-col; B = c2 row frags, n = row)
// -> lane holds 4 contiguous out cols -> direct float4 residual RMW.
// LDS-free, barrier-free. 32 rows/block, wave w owns cols [w*64, w*64+64).
// ---------------------------------------------------------------------------
__global__ __launch_bounds__(256) void k3_conv1x1b(
    const unsigned short* __restrict__ c2b, const unsigned short* __restrict__ w2p,
    const float* __restrict__ bias3, const float* __restrict__ data,
    float* __restrict__ out)
{
    int tid = threadIdx.x;
    int lane = tid & 63, wave = tid >> 6;
    int g = lane >> 4, r = lane & 15;
    int rowbase = blockIdx.x * 32;

    const short8_t* abase = (const short8_t*)w2p;
    short8_t bfr[2][2];
#pragma unroll
    for (int sub = 0; sub < 2; sub++)
#pragma unroll
        for (int s = 0; s < 2; s++)
            bfr[sub][s] = *(const short8_t*)(c2b + (size_t)(rowbase + sub * 16 + r) * CB + s * 32 + g * 8);

    f32x4 acc2[2][4] = {};
#pragma unroll
    for (int mt = 0; mt < 4; mt++) {
        short8_t a0 = abase[(wave * 4 + mt) * 64 + lane];          // s=0
        short8_t a1 = abase[(16 + wave * 4 + mt) * 64 + lane];     // s=1
        acc2[0][mt] = mfma16(a0, bfr[0][0], acc2[0][mt]);
        acc2[0][mt] = mfma16(a1, bfr[0][1], acc2[0][mt]);
        acc2[1][mt] = mfma16(a0, bfr[1][0], acc2[1][mt]);
        acc2[1][mt] = mfma16(a1, bfr[1][1], acc2[1][mt]);
    }

#pragma unroll
    for (int sub = 0; sub < 2; sub++)
#pragma unroll
        for (int mt = 0; mt < 4; mt++) {
            int col0 = (wave * 4 + mt) * 16 + g * 4;
            int rowg = rowbase + sub * 16 + r;
            float4 bs = *(const float4*)(bias3 + col0);
            float4 dv = *(const float4*)(data + (size_t)rowg * CIN + col0);
            f32x4 v = acc2[sub][mt];
            float4 res;
            res.x = fmaxf(v[0] + bs.x + dv.x, 0.f);
            res.y = fmaxf(v[1] + bs.y + dv.y, 0.f);
            res.z = fmaxf(v[2] + bs.z + dv.z, 0.f);
            res.w = fmaxf(v[3] + bs.w + dv.w, 0.f);
            *(float4*)(out + (size_t)rowg * CIN + col0) = res;
        }
}

extern "C" void kernel_launch(void* const* d_in, const int* in_sizes, int n_in,
                              void* d_out, int out_size, void* d_ws, size_t ws_size,
                              hipStream_t stream)
{
    const float* data = (const float*)d_in[0];
    const int* neigh  = (const int*)d_in[1];
    const float* w1 = (const float*)d_in[3];
    const float* g1 = (const float*)d_in[4];
    const float* b1 = (const float*)d_in[5];
    const float* m1 = (const float*)d_in[6];
    const float* v1 = (const float*)d_in[7];
    const float* w3 = (const float*)d_in[8];
    const float* g2 = (const float*)d_in[9];
    const float* b2 = (const float*)d_in[10];
    const float* m2 = (const float*)d_in[11];
    const float* v2 = (const float*)d_in[12];
    const float* w2 = (const float*)d_in[13];
    const float* g3 = (const float*)d_in[14];
    const float* b3 = (const float*)d_in[15];
    const float* m3 = (const float*)d_in[16];
    const float* v3 = (const float*)d_in[17];
    float* out = (float*)d_out;

    char* ws = (char*)d_ws;
    unsigned short* c1b = (unsigned short*)ws;                              // 16 MB
    unsigned short* c2b = (unsigned short*)(ws + 16777216);                 // 16 MB
    unsigned short* w1p = (unsigned short*)(ws + 33554432);                 // 32 KB
    unsigned short* w3p = (unsigned short*)(ws + 33554432 + 32768);         // 216 KB
    unsigned short* w2p = (unsigned short*)(ws + 33554432 + 32768 + 221184);// 32 KB
    float* bias1 = (float*)(ws + 33554432 + 32768 + 221184 + 32768);
    float* bias2 = bias1 + 64;
    float* bias3 = bias1 + 128;

    int n = in_sizes[0] / CIN;   // 131072

    hipLaunchKernelGGL(prep_kernel, dim3(562), dim3(256), 0, stream,
                       w1, w3, w2, g1, b1, m1, v1, g2, b2, m2, v2, g3, b3, m3, v3,
                       w1p, w3p, w2p, bias1, bias2, bias3);
    hipLaunchKernelGGL(k1_conv1x1a, dim3(n / 128), dim3(256), 0, stream, data, w1p, bias1, c1b);
    hipLaunchKernelGGL(k2_conv3x3,  dim3(n / 32),  dim3(64),  0, stream, c1b, neigh, w3p, bias2, c2b);
    hipLaunchKernelGGL(k3_conv1x1b, dim3(n / 32),  dim3(256), 0, stream, c2b, w2p, bias3, data, out);
}